// Round 10
// baseline (68.843 us; speedup 1.0000x reference)
//
#include <hip/hip_runtime.h>

// b=4, f=6, n_slots=7, n_buffer=8, h=w=128, 3 channels. bf=24.
constexpr int NB  = 8;
constexpr int NS  = 7;
constexpr int NCH = 3;
constexpr int HW  = 128 * 128;    // 16384
constexpr int HW2 = HW / 2;       // float2 per plane
constexpr int BF  = 24;
constexpr int BLOCK = 256;
constexpr int PXCHUNKS = HW / (BLOCK * 2);       // 32 px-chunks (512 px each)
constexpr int BLOCKS_PER_BF = PXCHUNKS * 2;      // 64 (x2 c-halves)
constexpr int NPART = BF * BLOCKS_PER_BF;        // 1536 blocks / partials
constexpr float INV_HW = 1.0f / (float)HW;
constexpr float SCALE  = 20.0f / (4.0f * 6.0f * 7.0f * 8.0f);
constexpr float LOG_CLAMP = -100.0f;

__global__ __launch_bounds__(BLOCK, 4)   // VGPR cap 128: ~110 live, NO spill (R8-proven)
void em_loss_kernel(const float* __restrict__ seg,
                    const float* __restrict__ masks,
                    const float* __restrict__ rec,
                    const float* __restrict__ rtgt,
                    const float* __restrict__ mvis,
                    const float* __restrict__ ai,
                    float* __restrict__ part,
                    unsigned* __restrict__ counter,
                    float* __restrict__ out) {
    const int bid  = blockIdx.x;
    const int bf   = bid >> 6;                   // / BLOCKS_PER_BF
    const int rem  = bid & 63;
    // bit3 = c-half so the two blocks sharing a px-chunk are 8 apart in
    // blockIdx -> same XCD under round-robin dispatch -> L2 dedups shared reads.
    const int half  = (rem >> 3) & 1;
    const int chunk = (rem & 7) | ((rem >> 4) << 3);   // 0..31
    const int tid   = threadIdx.x;
    const int v2    = chunk * BLOCK + tid;       // float2 index in plane
    const int c0    = half * 4;

    __shared__ float ai_s[NS][NB];
    __shared__ float A_s[NB];
    if (tid < NS * NB)
        ((float*)ai_s)[tid] = ai[bf * NS * NB + tid];
    __syncthreads();
    if (tid < NB) {
        float a = 0.f;
        #pragma unroll
        for (int s = 0; s < NS; ++s) a += ai_s[s][tid];
        A_s[tid] = a;
    }
    __syncthreads();

    const float2* segp = (const float2*)(seg  + (size_t)bf * NB * HW)       + v2;
    const float2* mp   = (const float2*)(masks + (size_t)bf * NS * HW)      + v2;
    const float2* rp   = (const float2*)(rec  + (size_t)bf * NB * NCH * HW) + v2;
    const float2* tp   = (const float2*)(rtgt + (size_t)bf * NCH * HW)      + v2;
    const float2* vp   = (const float2*)(mvis + (size_t)bf * NS * HW)       + v2;

    // ---- masks/mvis first; their float2s die into 0/1 bits ----
    float2 mv[NS], vv[NS];
    #pragma unroll
    for (int s = 0; s < NS; ++s) mv[s] = mp[s * HW2];
    #pragma unroll
    for (int s = 0; s < NS; ++s) vv[s] = vp[s * HW2];

    float2 tv[NCH];
    #pragma unroll
    for (int ch = 0; ch < NCH; ++ch) tv[ch] = tp[ch * HW2];

    // seg + rec for this block's 4 buffers
    float2 sv[4];
    #pragma unroll
    for (int c4 = 0; c4 < 4; ++c4) sv[c4] = segp[(c0 + c4) * HW2];

    float2 rr[4][NCH];
    #pragma unroll
    for (int c4 = 0; c4 < 4; ++c4)
        #pragma unroll
        for (int ch = 0; ch < NCH; ++ch)
            rr[c4][ch] = rp[((c0 + c4) * NCH + ch) * HW2];

    // ---- Compute ----
    float mb[NS][2], vb[NS][2];
    #pragma unroll
    for (int s = 0; s < NS; ++s) {
        mb[s][0] = (mv[s].x > 0.5f) ? 1.f : 0.f;
        mb[s][1] = (mv[s].y > 0.5f) ? 1.f : 0.f;
        vb[s][0] = (vv[s].x > 0.5f) ? 1.f : 0.f;
        vb[s][1] = (vv[s].y > 0.5f) ? 1.f : 0.f;
    }

    float acc = 0.f;
    #pragma unroll
    for (int c4 = 0; c4 < 4; ++c4) {
        const int c = c0 + c4;
        const float Ac = A_s[c];
        const float* sp  = (const float*)&sv[c4];
        const float* r0p = (const float*)&rr[c4][0];
        const float* r1p = (const float*)&rr[c4][1];
        const float* r2p = (const float*)&rr[c4][2];
        const float* t0p = (const float*)&tv[0];
        const float* t1p = (const float*)&tv[1];
        const float* t2p = (const float*)&tv[2];
        #pragma unroll
        for (int j = 0; j < 2; ++j) {
            float s  = sp[j];
            float lp = fmaxf(__logf(s), LOG_CLAMP);
            float l1 = fmaxf(__logf(1.0f - s), LOG_CLAMP);
            float d0 = r0p[j] - t0p[j];
            float d1 = r1p[j] - t1p[j];
            float d2 = r2p[j] - t2p[j];
            float D  = d0 * d0 + d1 * d1 + d2 * d2;
            float U = 0.f, V = 0.f;
            #pragma unroll
            for (int s7 = 0; s7 < NS; ++s7) {
                float a = ai_s[s7][c];
                U = fmaf(mb[s7][j], a, U);
                V = fmaf(vb[s7][j], a, V);
            }
            acc += -(Ac * l1 + U * (lp - l1)) * INV_HW + 0.1f * V * D;
        }
    }

    // wave reduce, cross-wave via LDS, one plain store per block
    #pragma unroll
    for (int off = 32; off; off >>= 1) acc += __shfl_down(acc, off, 64);
    __shared__ float wsum[BLOCK / 64];
    const int wid  = tid >> 6;
    const int lane = tid & 63;
    if (lane == 0) wsum[wid] = acc;
    __syncthreads();

    // ---- fused final reduction: last block to finish sums all partials ----
    __shared__ bool last;
    if (tid == 0) {
        part[bid] = wsum[0] + wsum[1] + wsum[2] + wsum[3];
        __threadfence();                          // publish partial before count
        last = (atomicAdd(counter, 1u) == NPART - 1);
    }
    __syncthreads();
    if (last) {
        __threadfence();                          // acquire all partials
        float a = 0.f;
        #pragma unroll
        for (int i = 0; i < NPART / BLOCK; ++i)   // 6 each
            a += part[i * BLOCK + tid];
        #pragma unroll
        for (int off = 32; off; off >>= 1) a += __shfl_down(a, off, 64);
        if (lane == 0) wsum[wid] = a;
        __syncthreads();
        if (tid == 0)
            out[0] = (wsum[0] + wsum[1] + wsum[2] + wsum[3]) * SCALE;
    }
}

extern "C" void kernel_launch(void* const* d_in, const int* in_sizes, int n_in,
                              void* d_out, int out_size, void* d_ws, size_t ws_size,
                              hipStream_t stream) {
    const float* seg   = (const float*)d_in[0];  // (4,6,8,128,128)
    const float* masks = (const float*)d_in[1];  // (4,6,7,128,128)
    const float* rec   = (const float*)d_in[2];  // (4,6,8,3,128,128)
    const float* rtgt  = (const float*)d_in[3];  // (4,6,3,128,128)
    const float* mvis  = (const float*)d_in[4];  // (4,6,7,128,128)
    const float* ai    = (const float*)d_in[5];  // (4,6,7,8)
    float* out  = (float*)d_out;
    float* part = (float*)d_ws;                  // NPART floats + 1 uint counter
    unsigned* counter = (unsigned*)(part + NPART);

    hipMemsetAsync(counter, 0, sizeof(unsigned), stream);
    em_loss_kernel<<<NPART, BLOCK, 0, stream>>>(seg, masks, rec, rtgt, mvis, ai,
                                                part, counter, out);
}